// Round 15
// baseline (6049.554 us; speedup 1.0000x reference)
//
#include <hip/hip_runtime.h>
#include <cstdint>

typedef short bf16x8 __attribute__((ext_vector_type(8)));
typedef float f32x4 __attribute__((ext_vector_type(4)));

#define MFMA(a,b,c) __builtin_amdgcn_mfma_f32_16x16x32_bf16((a),(b),(c),0,0,0)
#define GLOAD(dst, addr) asm volatile("global_load_dwordx4 %0, %1, off" : "=&v"(dst) : "v"(addr))
#define VWAIT3 do { asm volatile("s_waitcnt vmcnt(3)" ::: "memory"); __builtin_amdgcn_sched_barrier(0); } while(0)
#define VWAIT1 do { asm volatile("s_waitcnt vmcnt(1)" ::: "memory"); __builtin_amdgcn_sched_barrier(0); } while(0)
#define VWAIT0 do { asm volatile("s_waitcnt vmcnt(0)" ::: "memory"); __builtin_amdgcn_sched_barrier(0); } while(0)

// ---------------- ws layout (bytes) ----------------
constexpr int FR = 512;                          // bf16 elems per fragment (64 lanes x 8)
constexpr size_t OP2   = 0;                                  // P2 f32 [512rt][42nt][64][4]
constexpr size_t SZP2  = (size_t)512*42*256*4;               // 22,020,096
constexpr size_t OWSUM = OP2 + SZP2;                         // [25ks][42nt][512] bf16
constexpr size_t SZWSUM= (size_t)25*42*FR*2;
constexpr size_t OWEAM = OWSUM + SZWSUM;                     // enc A-side weights mu [28][21][512]
constexpr size_t SZWEA = (size_t)28*21*FR*2;
constexpr size_t OWEAL = OWEAM + SZWEA;
constexpr size_t OWEBM = OWEAL + SZWEA;                      // enc h-side [4][21][512]
constexpr size_t SZWEB = (size_t)4*21*FR*2;
constexpr size_t OWEBL = OWEBM + SZWEB;
constexpr size_t OWH   = OWEBL + SZWEB;                      // heads [8][14][512]
constexpr size_t SZWH  = (size_t)8*14*FR*2;
constexpr size_t OWD   = OWH + SZWH;                         // dec [8][21][512]
constexpr size_t SZWD  = (size_t)8*21*FR*2;
constexpr size_t OWW   = OWD + SZWD;                         // write [4][49][512]
constexpr size_t SZWW  = (size_t)4*49*FR*2;
constexpr size_t OBP2  = OWW + SZWW;                         // f32 bias frags
constexpr size_t OBGHN = OBP2 + (size_t)42*256*4;
constexpr size_t OBDI  = OBGHN + (size_t)2*7*256*4;
constexpr size_t OBDHN = OBDI + (size_t)21*256*4;
constexpr size_t OBWR  = OBDHN + (size_t)7*256*4;
constexpr size_t OBH   = OBWR + (size_t)49*256*4;            // end ~25.1 MB

__device__ __forceinline__ float sigf(float x){ return 1.0f/(1.0f+__expf(-x)); }
__device__ __forceinline__ float tanhfast(float x){ return 1.0f - 2.0f/(__expf(2.0f*x)+1.0f); }
__device__ __forceinline__ float bf2f(unsigned short u){ return __uint_as_float(((unsigned int)u)<<16); }
__device__ __forceinline__ unsigned short f2bf(float f){ unsigned int x = __float_as_uint(f); return (unsigned short)((x + 0x8000u) >> 16); }

// ---------------- weight / bias fragment packing ----------------
__global__ void init_pack(
    const float* __restrict__ ihmu, const float* __restrict__ whhmu,
    const float* __restrict__ bihmu, const float* __restrict__ bhhmu,
    const float* __restrict__ ihlv, const float* __restrict__ whhlv,
    const float* __restrict__ bihlv, const float* __restrict__ bhhlv,
    const float* __restrict__ wmu, const float* __restrict__ bmu,
    const float* __restrict__ wlv, const float* __restrict__ blv,
    const float* __restrict__ ihd, const float* __restrict__ whhd,
    const float* __restrict__ bihd, const float* __restrict__ bhhd,
    const float* __restrict__ wwr, const float* __restrict__ bwr,
    char* __restrict__ wsb)
{
  int u = blockIdx.x*256 + threadIdx.x;
  if (u < 1469440) {
    int v = u; size_t off; int NT; int region;
    if      (v < 537600)            { region=0; off=OWSUM; NT=42; }
    else if ((v-=537600) < 301056)  { region=1; off=OWEAM; NT=21; }
    else if ((v-=301056) < 301056)  { region=2; off=OWEAL; NT=21; }
    else if ((v-=301056) < 43008)   { region=3; off=OWEBM; NT=21; }
    else if ((v-=43008)  < 43008)   { region=4; off=OWEBL; NT=21; }
    else if ((v-=43008)  < 57344)   { region=5; off=OWH;   NT=14; }
    else if ((v-=57344)  < 86016)   { region=6; off=OWD;   NT=21; }
    else    { v-=86016;   region=7; off=OWW;   NT=49; }
    int ks = v / (NT*512); int rem = v - ks*(NT*512);
    int nt = rem >> 9; int li = rem & 511;
    int l = li >> 3, e = li & 7;
    int k = ks*32 + ((l>>4)<<3) + e;
    int c = l & 15;
    float val = 0.f;
    if (region==0) {
      int gru = nt/21, ntg = nt%21, gate = ntg/7, j = (ntg%7)*16 + c;
      if (j<100 && k<784) { const float* IH = gru? ihlv : ihmu; int jj = gate*100+j;
        val = IH[(size_t)jj*1668 + k] + IH[(size_t)jj*1668 + 784 + k]; }
    } else if (region==1 || region==2) {
      const float* IH = (region==2)? ihlv : ihmu;
      int gate = nt/7, j = (nt%7)*16 + c;
      if (j<100) { int jj = gate*100+j;
        if (k<784)      val = -IH[(size_t)jj*1668 + 784 + k];
        else if (k<884) val =  IH[(size_t)jj*1668 + 1568 + (k-784)]; }
    } else if (region==3 || region==4) {
      const float* WHH = (region==4)? whhlv : whhmu;
      int gate = nt/7, j = (nt%7)*16 + c;
      if (j<100 && k<100) val = WHH[(gate*100+j)*100 + k];
    } else if (region==5) {
      int grp = nt/7, j = (nt%7)*16 + c;
      if (j<100) {
        if (grp==0) { if (k<100) val = wmu[j*100+k]; }
        else        { if (k>=128 && k<228) val = wlv[j*100 + (k-128)]; }
      }
    } else if (region==6) {
      int gate = nt/7, j = (nt%7)*16 + c;
      if (j<100) { int jj = gate*100+j;
        if (k<100)               val = ihd[jj*100+k];
        else if (k>=128 && k<228) val = whhd[jj*100 + (k-128)]; }
    } else {
      int n = nt*16 + c;
      if (k<100) val = wwr[n*100+k];
    }
    *(unsigned short*)(wsb + off + (size_t)v*2) = f2bf(val);
    return;
  }
  u -= 1469440;
  if (u >= 37632) return;
  float val = 0.f; size_t off; int v = u;
  if (v < 10752) { off = OBP2;
    int nt = v>>8, li = v&255, l = li>>2, c = l&15;
    int gru = nt/21, ntg = nt%21, gate = ntg/7, j = (ntg%7)*16 + c;
    if (j<100) {
      const float* BI = gru? bihlv : bihmu; const float* BH = gru? bhhlv : bhhmu;
      val = BI[gate*100+j] + ((gate<2)? BH[gate*100+j] : 0.f);
    }
  } else if ((v-=10752) < 3584) { off = OBGHN;
    int g = v/1792, r2 = v - g*1792, p = r2>>8, li = r2&255, l = li>>2, c = l&15;
    int j = p*16+c;
    if (j<100) val = (g? bhhlv : bhhmu)[200+j];
  } else if ((v-=3584) < 5376) { off = OBDI;
    int nt = v>>8, li = v&255, l = li>>2, c = l&15;
    int gate = nt/7, j = (nt%7)*16+c;
    if (j<100) val = (gate<2)? (bihd[gate*100+j]+bhhd[gate*100+j]) : bihd[200+j];
  } else if ((v-=5376) < 1792) { off = OBDHN;
    int p = v>>8, li = v&255, l = li>>2, c = l&15; int j = p*16+c;
    if (j<100) val = bhhd[200+j];
  } else if ((v-=1792) < 12544) { off = OBWR;
    int nt = v>>8, li = v&255, l = li>>2, c = l&15;
    val = bwr[nt*16+c];
  } else { v -= 12544; off = OBH;
    int nt = v>>8, li = v&255, l = li>>2, c = l&15;
    int grp = nt/7, j = (nt%7)*16+c;
    if (j<100) val = grp? blv[j] : bmu[j];
  }
  *(float*)(wsb + off + (size_t)v*4) = val;
}

// ---------------- P2 = x@(W1+W2)^T + bias, fragment-packed f32 ----------------
__global__ __launch_bounds__(512) void init_p2(const float* __restrict__ x, char* __restrict__ wsb)
{
  __shared__ char xt[16*1600];
  const int tid = threadIdx.x, l = tid&63, w = tid>>6;
  const int lr = l&15, lg = l>>4;
  const int rt = blockIdx.x;
  for (int i = tid; i < 16*800; i += 512) {
    int row = i/800, col = i - row*800;
    unsigned short hv = 0;
    if (col < 784) hv = f2bf(x[(size_t)(rt*16+row)*784 + col]);
    *(unsigned short*)(xt + ((row*1600 + col*2) ^ ((row&7)<<4))) = hv;
  }
  __syncthreads();
  const char* WS = wsb + OWSUM;
  for (int nt = w; nt < 42; nt += 8) {
    f32x4 acc = *(const f32x4*)(wsb + OBP2 + (size_t)(nt*256 + l*4)*4);
    const char* wp = WS + (size_t)(nt*512 + l*8)*2;
    #pragma unroll 5
    for (int ks = 0; ks < 25; ++ks) {
      bf16x8 a = *(const bf16x8*)(xt + ((lr*1600 + ks*64 + lg*16) ^ ((lr&7)<<4)));
      bf16x8 b = *(const bf16x8*)(wp + (size_t)ks*42*512*2);
      acc = MFMA(a,b,acc);
    }
    *(f32x4*)(wsb + OP2 + ((size_t)(rt*42+nt)*64 + l)*16) = acc;
  }
}

// ------- main persistent kernel: 512 blocks x 1024 threads (16 waves), 16 rows -------
__global__ __launch_bounds__(1024,8) void draw_main(
    const float* __restrict__ noise, const char* __restrict__ wsb, float* __restrict__ out)
{
  extern __shared__ char sm[];
  char* Aenc = sm;               // [16][1792 B] bf16: sigc(784) | hdec(100) | pad
  char* Ahml = sm + 28672;       // [16][512 B]  bf16: hmu(100) pad | hlv(100) pad
  char* Adec = sm + 36864;       // [16][512 B]  bf16: z(100) pad | hdec(100) pad
  float* muv = (float*)(sm + 45056);   // [1600] mu | [1600] lv (f32)

  const int tid = threadIdx.x, l = tid&63, w = tid>>6;   // w in [0,16)
  const int lr = l&15, lg = l>>4;
  const int blk = blockIdx.x;

  float* out_c  = out;
  float* out_mu = out + (size_t)8192*784;
  float* out_lv = out_mu + (size_t)32*8192*100;

  for (int i = tid; i < 16*896; i += 1024) {
    int row = i/896, col = i - row*896;
    unsigned short v = (col<784)? (unsigned short)0x3F00 : (unsigned short)0;
    *(unsigned short*)(Aenc + ((row*1792 + col*2) ^ ((row&7)<<4))) = v;
  }
  for (int i = tid; i < 16*256; i += 1024) {
    int row = i>>8, col = i&255;
    int a = (row*512 + col*2) ^ ((row&7)<<4);
    *(unsigned short*)(Ahml + a) = 0;
    *(unsigned short*)(Adec + a) = 0;
  }

  // wave roles: 0-6 = mu path, 8-14 = lv+dec path, 7/15 = helper (z/store/write only)
  const bool isMu = (w < 7);
  const bool isLv = (w >= 8 && w < 15);
  const bool act  = isMu || isLv;
  const int p = isMu ? w : (w - 8);
  const int axor = (lr&7)<<4;

  const f32x4 z4 = {0.f,0.f,0.f,0.f};
  f32x4 p2j[3] = {z4,z4,z4};
  if (act) {
    size_t pb = OP2 + (((size_t)blk*42 + (isLv?21:0) + p)*64 + l)*16;
    p2j[0] = *(const f32x4*)(wsb + pb);
    p2j[1] = *(const f32x4*)(wsb + pb + (size_t)7*64*16);
    p2j[2] = *(const f32x4*)(wsb + pb + (size_t)14*64*16);
  }
  f32x4 creg[4] = {z4,z4,z4,z4};
  f32x4 hreg = z4;   // hm (mu waves) / hl (lv waves)
  f32x4 hd = z4;     // decoder state (lv waves)
  __syncthreads();

  for (int t = 0; t < 32; ++t) {
    // ---- noise prefetch: 1600 contiguous floats, fully coalesced ----
    float noz[2] = {0.f, 0.f};
    #pragma unroll
    for (int k2=0;k2<2;++k2) {
      int i = tid + k2*1024;
      if (i < 1600)
        noz[k2] = __builtin_nontemporal_load(noise + (size_t)t*819200 + (size_t)blk*1600 + i);
    }

    // ===== encoder GEMM, depth-2 asm-pipelined B stream (no dead prefetches) =====
    f32x4 ar=z4, az=z4, an=z4, ahn=z4;
    if (act) {
      ar = p2j[0]; az = p2j[1]; an = p2j[2];
      ahn = *(const f32x4*)(wsb + OBGHN + (size_t)(((isLv?7:0)+p)*256 + l*4)*4);
      const char* wr = wsb + (isLv? OWEAL : OWEAM) + (size_t)(p*512 + l*8)*2;
      int abase = lr*1792 + lg*16;
      bf16x8 e0,e1,e2,o0,o1,o2;
      GLOAD(e0, wr); GLOAD(e1, wr+7168); GLOAD(e2, wr+14336);
      #pragma unroll 2
      for (int ks=0; ks<26; ks+=2) {
        const char* p1 = wr + (size_t)(ks+1)*21504;
        GLOAD(o0, p1); GLOAD(o1, p1+7168); GLOAD(o2, p1+14336);
        VWAIT3;
        bf16x8 a = *(const bf16x8*)(Aenc + ((abase + ks*64) ^ axor));
        ar = MFMA(a, e0, ar); az = MFMA(a, e1, az); an = MFMA(a, e2, an);
        const char* p2 = wr + (size_t)(ks+2)*21504;
        GLOAD(e0, p2); GLOAD(e1, p2+7168); GLOAD(e2, p2+14336);
        VWAIT3;
        bf16x8 a2 = *(const bf16x8*)(Aenc + ((abase + (ks+1)*64) ^ axor));
        ar = MFMA(a2, o0, ar); az = MFMA(a2, o1, az); an = MFMA(a2, o2, an);
      }
      { // epilogue: slabs 26, 27
        const char* p1 = wr + (size_t)27*21504;
        GLOAD(o0, p1); GLOAD(o1, p1+7168); GLOAD(o2, p1+14336);
        VWAIT3;
        bf16x8 a = *(const bf16x8*)(Aenc + ((abase + 26*64) ^ axor));
        ar = MFMA(a, e0, ar); az = MFMA(a, e1, az); an = MFMA(a, e2, an);
        VWAIT0;
        bf16x8 a2 = *(const bf16x8*)(Aenc + ((abase + 27*64) ^ axor));
        ar = MFMA(a2, o0, ar); az = MFMA(a2, o1, az); an = MFMA(a2, o2, an);
      }
      // h-side: 4 slabs, fully unrolled pipeline, no dead loads
      const char* vr = wsb + (isLv? OWEBL : OWEBM) + (size_t)(p*512 + l*8)*2;
      int hb = lr*512 + (isLv?256:0) + lg*16;
      GLOAD(e0, vr); GLOAD(e1, vr+7168); GLOAD(e2, vr+14336);
      {
        const char* q1 = vr + 21504;
        GLOAD(o0,q1); GLOAD(o1,q1+7168); GLOAD(o2,q1+14336);
        VWAIT3;
        bf16x8 a = *(const bf16x8*)(Ahml + ((hb + 0*64) ^ axor));
        ar  = MFMA(a, e0, ar); az  = MFMA(a, e1, az); ahn = MFMA(a, e2, ahn);
        const char* q2 = vr + 2*21504;
        GLOAD(e0,q2); GLOAD(e1,q2+7168); GLOAD(e2,q2+14336);
        VWAIT3;
        bf16x8 a1 = *(const bf16x8*)(Ahml + ((hb + 1*64) ^ axor));
        ar  = MFMA(a1, o0, ar); az  = MFMA(a1, o1, az); ahn = MFMA(a1, o2, ahn);
        const char* q3 = vr + 3*21504;
        GLOAD(o0,q3); GLOAD(o1,q3+7168); GLOAD(o2,q3+14336);
        VWAIT3;
        bf16x8 a2 = *(const bf16x8*)(Ahml + ((hb + 2*64) ^ axor));
        ar  = MFMA(a2, e0, ar); az  = MFMA(a2, e1, az); ahn = MFMA(a2, e2, ahn);
        VWAIT0;
        bf16x8 a3 = *(const bf16x8*)(Ahml + ((hb + 3*64) ^ axor));
        ar  = MFMA(a3, o0, ar); az  = MFMA(a3, o1, az); ahn = MFMA(a3, o2, ahn);
      }
    }
    __syncthreads();                       // B1: Ahml reads done
    if (act) {
      int col = p*16 + lr;
      #pragma unroll
      for (int e=0;e<4;++e) {
        float rg = sigf(ar[e]);
        float zg = sigf(az[e]);
        float nn = tanhfast(fmaf(rg, ahn[e], an[e]));
        float hnew = nn + zg*(hreg[e] - nn);
        hreg[e] = hnew;
        if (col < 100) {
          int row = lg*4 + e;
          *(unsigned short*)(Ahml + ((row*512 + ((isLv?128:0)+col)*2) ^ ((row&7)<<4))) = f2bf(hnew);
        }
      }
    }
    __syncthreads();                       // B2: hmu/hlv ready

    // ===== heads (plain; compiler-managed waits) =====
    if (isMu) {
      f32x4 am = *(const f32x4*)(wsb + OBH + (size_t)(p*256 + l*4)*4);
      const char* WH = wsb + OWH;
      int hb = lr*512 + lg*16;
      #pragma unroll
      for (int ks=0; ks<4; ++ks) {
        bf16x8 a0 = *(const bf16x8*)(Ahml + ((hb + ks*64) ^ axor));
        am = MFMA(a0, *(const bf16x8*)(WH + ((size_t)(ks*14+p)*512 + l*8)*2), am);
      }
      int col = p*16 + lr;
      if (col < 100) {
        #pragma unroll
        for (int e=0;e<4;++e)
          muv[(lg*4+e)*100 + col] = fmaxf(am[e], 0.f);
      }
    } else if (isLv) {
      f32x4 al = *(const f32x4*)(wsb + OBH + (size_t)((7+p)*256 + l*4)*4);
      const char* WH = wsb + OWH;
      int hb = lr*512 + 256 + lg*16;
      #pragma unroll
      for (int ks=0; ks<4; ++ks) {
        bf16x8 a1 = *(const bf16x8*)(Ahml + ((hb + ks*64) ^ axor));
        al = MFMA(a1, *(const bf16x8*)(WH + ((size_t)((ks+4)*14+7+p)*512 + l*8)*2), al);
      }
      int col = p*16 + lr;
      if (col < 100) {
        #pragma unroll
        for (int e=0;e<4;++e)
          muv[1600 + (lg*4+e)*100 + col] = fmaxf(al[e], 0.f);
      }
    }
    __syncthreads();                       // B3: muv complete

    // ===== z-compute (elementwise) + dense store of mu/lv =====
    #pragma unroll
    for (int k2=0;k2<2;++k2) {
      int i = tid + k2*1024;
      if (i < 1600) {
        float m  = muv[i];
        float lv = muv[1600 + i];
        float zz = fmaf(noz[k2], __expf(0.5f*lv), m);
        int row = i/100, col = i - row*100;
        *(unsigned short*)(Adec + ((row*512 + col*2) ^ ((row&7)<<4))) = f2bf(zz);
      }
    }
    {
      size_t mb = (size_t)t*819200 + (size_t)blk*1600;
      if (tid < 800) {
        bool m0 = tid < 400;
        int k = m0 ? tid : tid - 400;
        f32x4 v = ((const f32x4*)muv)[tid];
        *((f32x4*)((m0 ? out_mu : out_lv) + mb) + k) = v;
      }
    }
    __syncthreads();                       // B4: Adec z ready

    // ===== decoder GRU (lv waves), depth-2 asm-pipelined, no dead loads =====
    f32x4 dr=z4, dz=z4, dn=z4, dhn=z4;
    if (isLv) {
      dr  = *(const f32x4*)(wsb + OBDI  + (size_t)(p*256 + l*4)*4);
      dz  = *(const f32x4*)(wsb + OBDI  + (size_t)((p+7)*256 + l*4)*4);
      dn  = *(const f32x4*)(wsb + OBDI  + (size_t)((p+14)*256 + l*4)*4);
      dhn = *(const f32x4*)(wsb + OBDHN + (size_t)(p*256 + l*4)*4);
      const char* br = wsb + OWD + (size_t)(p*512 + l*8)*2;
      int abase = lr*512 + lg*16;
      bf16x8 e0,e1,e2,o0,o1,o2;
      GLOAD(e0, br); GLOAD(e1, br+7168); GLOAD(e2, br+14336);
      #pragma unroll
      for (int ks=0; ks<6; ks+=2) {
        const char* q1 = br + (size_t)(ks+1)*21504;
        GLOAD(o0, q1); GLOAD(o1, q1+7168); GLOAD(o2, q1+14336);
        VWAIT3;
        bf16x8 a = *(const bf16x8*)(Adec + ((abase + ks*64) ^ axor));
        dr = MFMA(a, e0, dr); dz = MFMA(a, e1, dz);
        if (ks<4) dn = MFMA(a, e2, dn); else dhn = MFMA(a, e2, dhn);
        const char* q2 = br + (size_t)(ks+2)*21504;
        GLOAD(e0, q2); GLOAD(e1, q2+7168); GLOAD(e2, q2+14336);
        VWAIT3;
        bf16x8 a2 = *(const bf16x8*)(Adec + ((abase + (ks+1)*64) ^ axor));
        dr = MFMA(a2, o0, dr); dz = MFMA(a2, o1, dz);
        if (ks+1<4) dn = MFMA(a2, o2, dn); else dhn = MFMA(a2, o2, dhn);
      }
      { // epilogue: slabs 6, 7 (both -> dhn)
        const char* q1 = br + (size_t)7*21504;
        GLOAD(o0, q1); GLOAD(o1, q1+7168); GLOAD(o2, q1+14336);
        VWAIT3;
        bf16x8 a = *(const bf16x8*)(Adec + ((abase + 6*64) ^ axor));
        dr = MFMA(a, e0, dr); dz = MFMA(a, e1, dz); dhn = MFMA(a, e2, dhn);
        VWAIT0;
        bf16x8 a2 = *(const bf16x8*)(Adec + ((abase + 7*64) ^ axor));
        dr = MFMA(a2, o0, dr); dz = MFMA(a2, o1, dz); dhn = MFMA(a2, o2, dhn);
      }
    }
    __syncthreads();                       // B5: Adec reads done
    if (isLv) {
      int col = p*16 + lr;
      #pragma unroll
      for (int e=0;e<4;++e) {
        float rg = sigf(dr[e]);
        float zg = sigf(dz[e]);
        float nn = tanhfast(fmaf(rg, dhn[e], dn[e]));
        float hnew = nn + zg*(hd[e] - nn);
        hd[e] = hnew;
        if (col < 100) {
          int row = lg*4 + e;
          unsigned short hb2 = f2bf(hnew);
          *(unsigned short*)(Adec + ((row*512 + (128+col)*2) ^ ((row&7)<<4))) = hb2;
          *(unsigned short*)(Aenc + ((row*1792 + (784+col)*2) ^ ((row&7)<<4))) = hb2;
        }
      }
    }
    __syncthreads();                       // B6: new hdec visible

    // ===== canvas write GEMM: all 16 waves, depth-2 pipelined, no dead loads =====
    {
      const char* WW = wsb + OWW;
      #pragma unroll
      for (int rep=0; rep<4; ++rep) {
        int nt = w + rep*16;
        if (nt < 49) {
          f32x4 c = creg[rep];
          int abase = lr*512 + 256 + lg*16;
          const char* wwp = WW + ((size_t)nt*512 + l*8)*2;
          bf16x8 we, wo;
          GLOAD(we, wwp);
          GLOAD(wo, wwp + 50176);
          VWAIT1;
          bf16x8 a0 = *(const bf16x8*)(Adec + ((abase + 0*64) ^ axor));
          c = MFMA(a0, we, c);
          GLOAD(we, wwp + 2*50176);
          VWAIT1;
          bf16x8 a1 = *(const bf16x8*)(Adec + ((abase + 1*64) ^ axor));
          c = MFMA(a1, wo, c);
          GLOAD(wo, wwp + 3*50176);
          VWAIT1;
          bf16x8 a2 = *(const bf16x8*)(Adec + ((abase + 2*64) ^ axor));
          c = MFMA(a2, we, c);
          VWAIT0;
          bf16x8 a3 = *(const bf16x8*)(Adec + ((abase + 3*64) ^ axor));
          c = MFMA(a3, wo, c);
          f32x4 bw = *(const f32x4*)(wsb + OBWR + (size_t)(nt*256 + l*4)*4);
          c = c + bw;
          creg[rep] = c;
          #pragma unroll
          for (int e=0;e<4;++e) {
            float s = sigf(c[e]);
            int orow = lg*4 + e;
            int col = nt*16 + lr;
            if (t < 31) {
              *(unsigned short*)(Aenc + ((orow*1792 + col*2) ^ ((orow&7)<<4))) = f2bf(s);
            } else {
              out_c[(size_t)(blk*16+orow)*784 + col] = s;
            }
          }
        }
      }
    }
    __syncthreads();                       // B7: sigc ready for next step
  }
}

extern "C" void kernel_launch(void* const* d_in, const int* in_sizes, int n_in,
                              void* d_out, int out_size, void* d_ws, size_t ws_size,
                              hipStream_t stream) {
  (void)in_sizes; (void)n_in; (void)out_size; (void)ws_size;
  const float* x      = (const float*)d_in[0];
  const float* noise  = (const float*)d_in[1];
  const float* ih_mu  = (const float*)d_in[2];
  const float* whh_mu = (const float*)d_in[3];
  const float* bih_mu = (const float*)d_in[4];
  const float* bhh_mu = (const float*)d_in[5];
  const float* ih_lv  = (const float*)d_in[6];
  const float* whh_lv = (const float*)d_in[7];
  const float* bih_lv = (const float*)d_in[8];
  const float* bhh_lv = (const float*)d_in[9];
  const float* wmu    = (const float*)d_in[10];
  const float* bmu    = (const float*)d_in[11];
  const float* wlv    = (const float*)d_in[12];
  const float* blv    = (const float*)d_in[13];
  const float* wih_dec= (const float*)d_in[14];
  const float* whh_dec= (const float*)d_in[15];
  const float* bih_dec= (const float*)d_in[16];
  const float* bhh_dec= (const float*)d_in[17];
  const float* wwrite = (const float*)d_in[18];
  const float* bwrite = (const float*)d_in[19];
  char* wsb = (char*)d_ws;
  float* out = (float*)d_out;

  (void)hipFuncSetAttribute(reinterpret_cast<const void*>(draw_main),
                            hipFuncAttributeMaxDynamicSharedMemorySize, 57856);

  init_pack<<<5888, 256, 0, stream>>>(ih_mu, whh_mu, bih_mu, bhh_mu,
                                      ih_lv, whh_lv, bih_lv, bhh_lv,
                                      wmu, bmu, wlv, blv,
                                      wih_dec, whh_dec, bih_dec, bhh_dec,
                                      wwrite, bwrite, wsb);
  init_p2<<<512, 512, 0, stream>>>(x, wsb);
  draw_main<<<512, 1024, 57856, stream>>>(noise, wsb, out);
}